// Round 7
// baseline (81.952 us; speedup 1.0000x reference)
//
#include <hip/hip_runtime.h>

// AnchorProcessor v7 — DIAGNOSTIC build (v4 x4 inner repeat).
// Purpose: (1) push our dispatch above the 75us harness fills so rocprof's
// top-5 shows OUR counters (FETCH_SIZE, VALUBusy, Occupancy); (2) split
// HBM-rep vs L3-rep time: rep1 streams x from HBM, reps 2-4 re-read the same
// 133MB (fits 256MB L3). dur ~= k_hbm + 3*k_l3 + overhead.
// Correctness: reps re-scan identical data into the same running (max,idx)
// with strict '>' -> result provably identical to one pass. Boxes recomputed
// per rep, stored once (values identical).

#define NN   8
#define AA   3
#define CLSN 80
#define HW   16384           // 128*128
#define CH   255             // 3*85
#define REPS 4

__device__ __forceinline__ float sigf(float v) {
    return 1.0f / (1.0f + __expf(-v));
}

__global__ __launch_bounds__(512, 6)
void anchor_kernel_v7(const float* __restrict__ x, float* __restrict__ out) {
    const int lane = threadIdx.x & 63;     // pixel within 64-pixel group
    const int n    = threadIdx.x >> 6;     // wave id = batch index

    const int bid = blockIdx.x;
    const int a   = bid >> 8;              // 0..2
    const int pg  = bid & 255;             // 256 pixel-groups
    const int pix = pg * 64 + lane;        // flat pixel h*128+w
    const int h   = pix >> 7;
    const int w   = pix & 127;

    const float anchw[AA] = {116.f, 156.f, 373.f};
    const float anchh[AA] = { 90.f, 198.f, 326.f};

    const int abase = n * (CH * HW) + (a * 85) * HW + pix;
    const int obase = (n * 18 + a * 6) * HW + pix;

    float best = -__builtin_inff();
    int   bidx = 0x7fffffff;

    for (int rep = 0; rep < REPS; ++rep) {
        const float tx  = x[abase + 0 * HW];
        const float ty  = x[abase + 1 * HW];
        const float tw  = x[abase + 2 * HW];
        const float th  = x[abase + 3 * HW];
        const float obj = x[abase + 4 * HW];

        if (rep == REPS - 1) {
            out[obase + 0 * HW] = sigf(tx) + (float)w;
            out[obase + 1 * HW] = sigf(ty) + (float)h;
            out[obase + 2 * HW] = tw * anchw[a];
            out[obase + 3 * HW] = th * anchh[a];
        } else {
            // keep the box loads alive without stores
            asm volatile("" :: "v"(tx), "v"(ty), "v"(tw), "v"(th));
        }

        #pragma unroll 8
        for (int c = 0; c < CLSN; ++c) {
            const float v = x[abase + (5 + c) * HW] * obj;
            if (v > best) { best = v; bidx = n * CLSN + c; }
        }
    }

    __shared__ float s_val[NN][64];
    __shared__ int   s_idx[NN][64];
    s_val[n][lane] = best;
    s_idx[n][lane] = bidx;
    __syncthreads();

    float fbest = s_val[0][lane];
    int   fidx  = s_idx[0][lane];
    #pragma unroll
    for (int nn = 1; nn < NN; ++nn) {
        const float v  = s_val[nn][lane];
        const int   id = s_idx[nn][lane];
        if (v > fbest || (v == fbest && id < fidx)) { fbest = v; fidx = id; }
    }
    out[obase + 4 * HW] = fbest;
    out[obase + 5 * HW] = (float)fidx;
}

extern "C" void kernel_launch(void* const* d_in, const int* in_sizes, int n_in,
                              void* d_out, int out_size, void* d_ws, size_t ws_size,
                              hipStream_t stream) {
    const float* x = (const float*)d_in[0];
    float* out = (float*)d_out;
    dim3 grid(AA * 256);   // anchor x pixel-group
    dim3 block(512);
    hipLaunchKernelGGL(anchor_kernel_v7, grid, block, 0, stream, x, out);
}

// Round 8
// 27.463 us; speedup vs baseline: 2.9841x; 2.9841x over previous
//
#include <hip/hip_runtime.h>

// AnchorProcessor: x[8,255,128,128] f32 -> out[8,18,128,128] f32
// v8 == v4 (best, 27.6us). Wave w owns batch n=w; lane = 1 of 64 consecutive
// pixels -> every load instruction is ONE contiguous 256B segment. Block 512
// = 8 waves (all n); grid = 3 anchors x 256 pixel-groups = 768 blocks =
// 3 blocks/CU, 24 waves/CU. Per-(a,pixel) max/argmax over (n,c) completes
// in-block via LDS, first-max tie-break on flat idx n*80+c.
//
// Roofline case (v7 diagnostic): 133.7MB read @6.3TB/s + 9.4MB write + ~5us
// fixed replay overhead = 27.5us; L3-resident rescan still costs 18.1us
// (7.4TB/s on-chip path cap) -> no access-pattern change can help materially.

#define NN   8
#define AA   3
#define CLSN 80
#define HW   16384           // 128*128
#define CH   255             // 3*85

__device__ __forceinline__ float sigf(float v) {
    return 1.0f / (1.0f + __expf(-v));
}

__global__ __launch_bounds__(512, 6)
void anchor_kernel_v8(const float* __restrict__ x, float* __restrict__ out) {
    const int lane = threadIdx.x & 63;     // pixel within 64-pixel group
    const int n    = threadIdx.x >> 6;     // wave id = batch index

    const int bid = blockIdx.x;
    const int a   = bid >> 8;              // 0..2
    const int pg  = bid & 255;             // 256 pixel-groups
    const int pix = pg * 64 + lane;        // flat pixel h*128+w
    const int h   = pix >> 7;
    const int w   = pix & 127;

    const float anchw[AA] = {116.f, 156.f, 373.f};
    const float anchh[AA] = { 90.f, 198.f, 326.f};

    const int abase = n * (CH * HW) + (a * 85) * HW + pix;

    const float tx  = x[abase + 0 * HW];
    const float ty  = x[abase + 1 * HW];
    const float tw  = x[abase + 2 * HW];
    const float th  = x[abase + 3 * HW];
    const float obj = x[abase + 4 * HW];

    const int obase = (n * 18 + a * 6) * HW + pix;
    out[obase + 0 * HW] = sigf(tx) + (float)w;
    out[obase + 1 * HW] = sigf(ty) + (float)h;
    out[obase + 2 * HW] = tw * anchw[a];
    out[obase + 3 * HW] = th * anchh[a];

    // 80-class partial reduction for this n (flat idx = n*80+c, first-max)
    float best = -__builtin_inff();
    int   bidx = 0x7fffffff;
    #pragma unroll 8
    for (int c = 0; c < CLSN; ++c) {
        const float v = x[abase + (5 + c) * HW] * obj;
        if (v > best) { best = v; bidx = n * CLSN + c; }
    }

    __shared__ float s_val[NN][64];
    __shared__ int   s_idx[NN][64];
    s_val[n][lane] = best;
    s_idx[n][lane] = bidx;
    __syncthreads();

    // cross-n combine; identical result for all waves, each writes its own n.
    float fbest = s_val[0][lane];
    int   fidx  = s_idx[0][lane];
    #pragma unroll
    for (int nn = 1; nn < NN; ++nn) {
        const float v  = s_val[nn][lane];
        const int   id = s_idx[nn][lane];
        if (v > fbest || (v == fbest && id < fidx)) { fbest = v; fidx = id; }
    }
    out[obase + 4 * HW] = fbest;
    out[obase + 5 * HW] = (float)fidx;
}

extern "C" void kernel_launch(void* const* d_in, const int* in_sizes, int n_in,
                              void* d_out, int out_size, void* d_ws, size_t ws_size,
                              hipStream_t stream) {
    const float* x = (const float*)d_in[0];
    float* out = (float*)d_out;
    dim3 grid(AA * 256);   // anchor x pixel-group
    dim3 block(512);
    hipLaunchKernelGGL(anchor_kernel_v8, grid, block, 0, stream, x, out);
}